// Round 10
// baseline (178.811 us; speedup 1.0000x reference)
//
#include <hip/hip_runtime.h>

// LSTM (B=8192, T=256, in=1, H=64) + fc1(64->32,relu) + fc2(32->2).
// 32x32x16_f16 MFMA restructure. 256 blocks x 512 thr (8 waves) = 1 block/CU.
// Wave w owns one 32-row C-tile (unit-major gate packing: permuted row =
// unit*4+gate; tile w = units 8w..8w+7). C layout (col=lane&31=batch,
// row=(reg&3)+8(reg>>2)+4(lane>>5)) -> lane owns 4 COMPLETE cells
// (reg=4q+gate, unit=8w+2q+hi): 4-way ILP in the trans chain per lane.
// vs R9: LDS reads halve (8 waves x 64B/lane vs 32 waves x 32B/lane),
// barrier participants 16->8, 28 trans/lane with 4 independent chains.
// h: single fp16 plane [32][64], 128B rows, 16B-block XOR swizzle (blk^row&7).
// Cell: common-denominator form, 5 exp2 + 2 rcp per cell.

typedef __attribute__((ext_vector_type(8))) _Float16 f16x8;
typedef __attribute__((ext_vector_type(16))) float f32x16;

#define TT 256
#define BT 32
#define XPAD 260

#if __has_builtin(__builtin_amdgcn_exp2f)
#define EXP2F __builtin_amdgcn_exp2f
#else
#define EXP2F exp2f
#endif
#if __has_builtin(__builtin_amdgcn_rcpf)
#define RCPF __builtin_amdgcn_rcpf
#else
#define RCPF(x) (1.0f / (x))
#endif
#if __has_builtin(__builtin_amdgcn_fmed3f)
#define MED3F __builtin_amdgcn_fmed3f
#else
#define MED3F(a, lo, hi) fminf(fmaxf((a), (lo)), (hi))
#endif

#define NLOG2E  -1.4426950408889634f
#define N2LOG2E -2.8853900817779268f

__device__ __forceinline__ ushort f2h_bits(float f) {
    union { _Float16 h; ushort u; } v;
    v.h = (_Float16)f;
    return v.u;
}
__device__ __forceinline__ float h2f(ushort u) {
    union { ushort u; _Float16 h; } v;
    v.u = u;
    return (float)v.h;
}

__global__ __launch_bounds__(512, 2) void lstm_32(
    const float* __restrict__ x,      // [B,T]
    const float* __restrict__ W_ih,   // [256]
    const float* __restrict__ W_hh,   // [256][64]
    const float* __restrict__ b_ih,   // [256]
    const float* __restrict__ b_hh,   // [256]
    const float* __restrict__ fc1_w,  // [32][64]
    const float* __restrict__ fc1_b,  // [32]
    const float* __restrict__ fc2_w,  // [2][32]
    const float* __restrict__ fc2_b,  // [2]
    float* __restrict__ out)          // [B][2]
{
    __shared__ float  x_lds[BT][XPAD];
    __shared__ ushort h_pl[2][BT * 64];   // fp16, 128B rows, XOR-swizzled 16B blocks

    const int tid  = threadIdx.x;
    const int lane = tid & 63;
    const int w    = tid >> 6;       // wave 0..7 = M-tile (units 8w..8w+7)
    const int b31  = lane & 31;      // batch (C col / B-frag n); A-frag row m
    const int hi   = lane >> 5;      // 0..1 (k-half select)
    const int s7   = b31 & 7;        // swizzle key (row)
    const long long bBase = (long long)blockIdx.x * BT;

    // ---- stage x tile: 2048 float4s / 512 thr ----
    {
        const float4* xg = (const float4*)(x + bBase * TT);
        for (int i = tid; i < BT * TT / 4; i += 512) {
            int b = i >> 6, c4 = i & 63;
            *(float4*)&x_lds[b][c4 * 4] = xg[i];
        }
    }
    // ---- zero h buffer 0: 2048 ushorts = 512 x 8B ----
    ((unsigned long long*)h_pl[0])[tid] = 0ull;

    // ---- A-frags: W_hh unit-major permuted rows, fp16, pre-scaled ----
    // m = b31 -> unit = 8w + (m>>2), gate = m&3; k = kt*16 + hi*8 + j.
    const int gateA = b31 & 3;
    const int unitA = 8 * w + (b31 >> 2);
    const float sgA = (gateA == 2) ? N2LOG2E : NLOG2E;
    f16x8 Af[4];
#pragma unroll
    for (int kt = 0; kt < 4; ++kt) {
        const float* src = W_hh + (gateA * 64 + unitA) * 64 + kt * 16 + hi * 8;
#pragma unroll
        for (int j = 0; j < 8; ++j)
            Af[kt][j] = (_Float16)(src[j] * sgA);
    }

    // ---- per-lane cell params: reg r = 4q+g -> cell (b31, u=8w+2q+hi) ----
    float wih[16], bias[16];
#pragma unroll
    for (int r = 0; r < 16; ++r) {
        const int g = r & 3, q = r >> 2;
        const int u = 8 * w + 2 * q + hi;
        const float sg = (g == 2) ? N2LOG2E : NLOG2E;
        const int idx = g * 64 + u;
        wih[r]  = W_ih[idx] * sg;
        bias[r] = (b_ih[idx] + b_hh[idx]) * sg;
    }

    // ---- swizzled LDS offsets (ushort units), loop-invariant ----
    const int ro = b31 * 64;
    int rdOff[4], wrOff[4];
#pragma unroll
    for (int kt = 0; kt < 4; ++kt)
        rdOff[kt] = ro + (((2 * kt + hi) ^ s7) << 3);
#pragma unroll
    for (int q = 0; q < 4; ++q)
        wrOff[q] = ro + ((w ^ s7) << 3) + 2 * q + hi;

    float cst[4] = {0.f, 0.f, 0.f, 0.f};
    __syncthreads();

    // one LSTM step at compile-time-constant buffer p
    auto stepf = [&](int p, int t) {
        const f16x8 B0 = *(const f16x8*)&h_pl[p][rdOff[0]];
        const f16x8 B1 = *(const f16x8*)&h_pl[p][rdOff[1]];
        const f16x8 B2 = *(const f16x8*)&h_pl[p][rdOff[2]];
        const f16x8 B3 = *(const f16x8*)&h_pl[p][rdOff[3]];
        const float xr = x_lds[b31][t];

        f32x16 acc;
#pragma unroll
        for (int r = 0; r < 16; ++r) acc[r] = xr * wih[r] + bias[r];

        acc = __builtin_amdgcn_mfma_f32_32x32x16_f16(Af[0], B0, acc, 0, 0, 0);
        acc = __builtin_amdgcn_mfma_f32_32x32x16_f16(Af[1], B1, acc, 0, 0, 0);
        acc = __builtin_amdgcn_mfma_f32_32x32x16_f16(Af[2], B2, acc, 0, 0, 0);
        acc = __builtin_amdgcn_mfma_f32_32x32x16_f16(Af[3], B3, acc, 0, 0, 0);

        // 4 independent cell chains (i,f,g,o = acc[4q+0..3], pre-scaled)
#pragma unroll
        for (int q = 0; q < 4; ++q) {
            const float A_ = EXP2F(acc[4 * q + 0]);
            const float F_ = EXP2F(acc[4 * q + 1]);
            const float Bv = EXP2F(acc[4 * q + 2]);
            const float C_ = EXP2F(acc[4 * q + 3]);
            const float pA = 1.0f + A_, pF = 1.0f + F_, pB = 1.0f + Bv, pC = 1.0f + C_;
            const float P   = pA * pB;
            const float den = P * pF;
            const float num = cst[q] * P + (1.0f - Bv) * pF;
            const float cc  = num * RCPF(den);
            cst[q] = cc;
            const float targ = MED3F(N2LOG2E * cc, -60.0f, 60.0f);
            const float D  = EXP2F(targ);
            const float hn = (1.0f - D) * RCPF(pC * (1.0f + D));
            h_pl[p ^ 1][wrOff[q]] = f2h_bits(hn);
        }
        __syncthreads();
    };

#pragma unroll 1
    for (int t = 0; t < TT; t += 2) {
        stepf(0, t);       // reads buf0, writes buf1
        stepf(1, t + 1);   // reads buf1, writes buf0
    }
    // final h is in buffer 0

    // ---- tail: fc1 + relu into x_lds (x dead), then fc2 ----
    {
        const int b = tid >> 4;            // 0..31
        const int u2a = (tid & 15) * 2;    // 2 outputs per thread
#pragma unroll
        for (int q2 = 0; q2 < 2; ++q2) {
            const int u2 = u2a + q2;
            float a = fc1_b[u2];
            for (int k = 0; k < 64; ++k) {
                const int off = b * 64 + ((((k >> 3) ^ (b & 7))) << 3) + (k & 7);
                a += fc1_w[u2 * 64 + k] * h2f(h_pl[0][off]);
            }
            x_lds[b][u2] = a > 0.0f ? a : 0.0f;
        }
    }
    __syncthreads();
    if (tid < BT * 2) {
        const int b = tid >> 1, o = tid & 1;
        float a = fc2_b[o];
#pragma unroll
        for (int u2 = 0; u2 < 32; ++u2)
            a += x_lds[b][u2] * fc2_w[o * 32 + u2];
        out[(bBase + b) * 2 + o] = a;
    }
}

extern "C" void kernel_launch(void* const* d_in, const int* in_sizes, int n_in,
                              void* d_out, int out_size, void* d_ws, size_t ws_size,
                              hipStream_t stream) {
    const float* x     = (const float*)d_in[0];
    const float* W_ih  = (const float*)d_in[1];
    const float* W_hh  = (const float*)d_in[2];
    const float* b_ih  = (const float*)d_in[3];
    const float* b_hh  = (const float*)d_in[4];
    const float* fc1_w = (const float*)d_in[5];
    const float* fc1_b = (const float*)d_in[6];
    const float* fc2_w = (const float*)d_in[7];
    const float* fc2_b = (const float*)d_in[8];
    float* out = (float*)d_out;

    lstm_32<<<dim3(8192 / BT), dim3(512), 0, stream>>>(
        x, W_ih, W_hh, b_ih, b_hh, fc1_w, fc1_b, fc2_w, fc2_b, out);
}